// Round 7
// baseline (552.005 us; speedup 1.0000x reference)
//
#include <hip/hip_runtime.h>

// GRU-D: nf=64, B=128, T=100, I=64, H=128, C=256.
// R7: BB=16, 2 blocks/CU (128-VGPR cap). wz+wg in regs; wr/wh streamed from L2
//     (laundered loads). Fast tanh/sigmoid. XOR lane swizzle. 3 barriers/step.
#define NF 64
#define BATCH 128
#define TT 100
#define II 64
#define HH 128
#define CC 256
#define BB 16
#define NTHR 512
#define PSTRIDE 111297

#define OFF_ZW 0
#define OFF_ZB 32768
#define OFF_RW 32896
#define OFF_RB 65664
#define OFF_HW 65792
#define OFF_HB 98560
#define OFF_GXW 98688
#define OFF_GXB 102784
#define OFF_GHW 102848
#define OFF_GHB 111040
#define OFF_FCW 111168
#define OFF_FCB 111296

// ws layout (bf16 elems), per-lane MFMA B-fragment order (hi only):
//  frag addr = region + n*PER_N + (kt*NT + nt)*512 + l*8 + j
#define ZR_PER_N 65536
#define H_BASE   (64 * ZR_PER_N)
#define H_PER_N  32768
#define G_BASE   (H_BASE + 64 * H_PER_N)
#define G_PER_N  8192
#define WS_ELEMS (G_BASE + 64 * G_PER_N)   // 6815744 bf16 = 13 MB

typedef __bf16 bf16x8 __attribute__((ext_vector_type(8)));
typedef __bf16 bf16x2 __attribute__((ext_vector_type(2)));
typedef float f32x4 __attribute__((ext_vector_type(4)));
typedef float f32x2 __attribute__((ext_vector_type(2)));

__device__ __forceinline__ f32x4 mfma16(bf16x8 a, bf16x8 b, f32x4 c) {
  return __builtin_amdgcn_mfma_f32_16x16x32_bf16(a, b, c, 0, 0, 0);
}
__device__ __forceinline__ float rcpf_(float x) { return __builtin_amdgcn_rcpf(x); }
__device__ __forceinline__ float sigmoidf_(float x) { return rcpf_(1.f + __expf(-x)); }
__device__ __forceinline__ float tanhf_(float x) {
  float e = __expf(-2.f * __builtin_fabsf(x));
  float t = (1.f - e) * rcpf_(1.f + e);
  return x < 0.f ? -t : t;
}
// fragment-row swizzle (bank spreading): physical row = r ^ 2*(r>>4)
__device__ __forceinline__ int SW(int x) { return x ^ (((x >> 4) & 3) << 1); }

// ---- repack: params -> B-fragment-ordered bf16 (hi only) in ws ----
__global__ void repack_kernel(const float* __restrict__ p, __bf16* __restrict__ ws) {
  const int total = 4194304 + 2097152 + 524288;
  for (int e = blockIdx.x * 256 + threadIdx.x; e < total; e += gridDim.x * 256) {
    float wv; int dst;
    if (e < 4194304) {  // ZR: [z cols 0..127 | r cols 0..127], K=256
      int j = e & 7, l = (e >> 3) & 63, nt = (e >> 9) & 15, kt = (e >> 13) & 7, n = e >> 16;
      int c = kt * 32 + (l >> 4) * 8 + j, l15 = l & 15;
      long pn = (long)n * PSTRIDE;
      wv = (nt < 8) ? p[pn + OFF_ZW + (nt * 16 + l15) * CC + c]
                    : p[pn + OFF_RW + ((nt - 8) * 16 + l15) * CC + c];
      dst = n * ZR_PER_N + (kt * 16 + nt) * 512 + l * 8 + j;
    } else if (e < 4194304 + 2097152) {  // H: h_tilde weights, K=256
      int e2 = e - 4194304;
      int j = e2 & 7, l = (e2 >> 3) & 63, nt = (e2 >> 9) & 7, kt = (e2 >> 12) & 7, n = e2 >> 15;
      int c = kt * 32 + (l >> 4) * 8 + j, l15 = l & 15;
      wv = p[(long)n * PSTRIDE + OFF_HW + (nt * 16 + l15) * CC + c];
      dst = H_BASE + n * H_PER_N + (kt * 8 + nt) * 512 + l * 8 + j;
    } else {  // G: ghw [128][64], K=64
      int e2 = e - (4194304 + 2097152);
      int j = e2 & 7, l = (e2 >> 3) & 63, nt = (e2 >> 9) & 7, kt = (e2 >> 12) & 1, n = e2 >> 13;
      int c = kt * 32 + (l >> 4) * 8 + j, l15 = l & 15;
      wv = p[(long)n * PSTRIDE + OFF_GHW + (nt * 16 + l15) * II + c];
      dst = G_BASE + n * G_PER_N + (kt * 8 + nt) * 512 + l * 8 + j;
    }
    ws[dst] = (__bf16)wv;
  }
}

// One block per (n, 16-batch chunk); 8 waves; 2 blocks/CU.
// Wave w owns cols cw = w*16 + (l&15); h/z/r/h_tilde register-local per lane.
__global__ __launch_bounds__(NTHR, 4) void grud_main(
    const float* __restrict__ p, const float* __restrict__ X,
    const float* __restrict__ XL, const float* __restrict__ XM,
    const float* __restrict__ MK, const float* __restrict__ DE,
    const __bf16* __restrict__ ws, float* __restrict__ out) {
  // A-frag planes [.."kt"..][64][8]; row dimension stored XOR-swizzled (SW).
  __shared__ __align__(16) __bf16 xA_hi[2][2][64][8];  // [parity][kt]  k in [0,64)
  __shared__ __align__(16) __bf16 xA_lo[2][2][64][8];
  __shared__ __align__(16) __bf16 mA[2][2][64][8];     // k in [192,256), lo==0
  __shared__ __align__(16) __bf16 hA_hi[4][64][8];     // k in [64,192)
  __shared__ __align__(16) __bf16 hA_lo[4][64][8];
  __shared__ __align__(16) __bf16 rhA_hi[4][64][8];
  __shared__ __align__(16) __bf16 rhA_lo[4][64][8];
  __shared__ __align__(16) __bf16 dA_hi[2][2][64][8];  // [parity][kt]
  __shared__ __align__(16) __bf16 dA_lo[2][2][64][8];
  __shared__ float hstage[BB][132];

  const int tid = threadIdx.x;
  const int w = tid >> 6, l = tid & 63;
  const int l15 = l & 15, lg = l >> 4;
  const int n = blockIdx.x & 63;            // same-n blocks -> same XCD
  const int b0 = (blockIdx.x >> 6) * BB;
  const long pn = (long)n * PSTRIDE;
  const int cw = w * 16 + l15;
  const int sl = SW(l);                     // physical read-row for A-frags

  const __bf16* __restrict__ wzr_base = ws + n * ZR_PER_N;
  const __bf16* __restrict__ wh_base  = ws + H_BASE + n * H_PER_N;
  const __bf16* __restrict__ wg_base  = ws + G_BASE + n * G_PER_N;

  // static weights: z (32 VGPR) + g (8 VGPR); r/h streamed per step from L2
  bf16x8 wzR[8], wgR[2];
#pragma unroll
  for (int kt = 0; kt < 8; ++kt)
    wzR[kt] = *(const bf16x8*)(wzr_base + (kt * 16 + w) * 512 + l * 8);
#pragma unroll
  for (int kt = 0; kt < 2; ++kt)
    wgR[kt] = *(const bf16x8*)(wg_base + (kt * 8 + w) * 512 + l * 8);

  const float zb = p[pn + OFF_ZB + cw];
  const float rb = p[pn + OFF_RB + cw];
  const float hb = p[pn + OFF_HB + cw];
  const float gb = p[pn + OFF_GHB + cw];

  // this lane's h-column LDS coords: global k = 64 + cw
  const int hkt2 = ((64 + cw) >> 5) - 2;    // 0..3
  const int qh = (cw >> 3) & 3;             // 16-row group within plane
  const int hj = cw & 7;

  // phase-A mapping: thread -> (row 0..15, 2-wide i block)
  const int arow = tid >> 5;
  const int ai0 = (tid & 31) * 2;
  const int akt = ai0 >> 5;
  const int salane = SW(((ai0 >> 3) & 3) * 16 + arow);
  const int aj = ai0 & 7;
  const float* __restrict__ Xp  = X  + (long)(b0 + arow) * TT * II + ai0;
  const float* __restrict__ XLp = XL + (long)(b0 + arow) * TT * II + ai0;
  const float* __restrict__ MKp = MK + ((long)(n * BATCH + b0 + arow) * TT) * II + ai0;
  const float* __restrict__ DEp = DE + ((long)(n * BATCH + b0 + arow) * TT) * II + ai0;
  const float gxd0 = p[pn + OFF_GXW + ai0 * 65];
  const float gxd1 = p[pn + OFF_GXW + (ai0 + 1) * 65];
  const float gxb0 = p[pn + OFF_GXB + ai0];
  const float gxb1 = p[pn + OFF_GXB + ai0 + 1];

  float h[4] = {0.f, 0.f, 0.f, 0.f};

  // prefetch t=0 inputs
  f32x2 fx  = *(const f32x2*)Xp;
  f32x2 fxl = *(const f32x2*)XLp;
  f32x2 fxm = *(const f32x2*)(XM + ai0);
  f32x2 fm  = __builtin_nontemporal_load((const f32x2*)MKp);
  f32x2 fd  = __builtin_nontemporal_load((const f32x2*)DEp);

  for (int t = 0; t < TT; ++t) {
    const int par = t & 1;
    // ---- Phase A: elementwise x; write swizzled LDS A-frags (parity par) ----
    {
      float m0 = fm[0], m1 = fm[1], d0 = fd[0], d1 = fd[1];
      float dx0 = __expf(-fmaxf(fmaf(d0, gxd0, gxb0), 0.f));
      float dx1 = __expf(-fmaxf(fmaf(d1, gxd1, gxb1), 0.f));
      float xv0 = m0 * fx[0] + (1.f - m0) * (dx0 * fxl[0] + (1.f - dx0) * fxm[0]);
      float xv1 = m1 * fx[1] + (1.f - m1) * (dx1 * fxl[1] + (1.f - dx1) * fxm[1]);
      __bf16 x0h = (__bf16)xv0, x1h = (__bf16)xv1;
      __bf16 d0h = (__bf16)d0, d1h = (__bf16)d1;
      *(bf16x2*)&xA_hi[par][akt][salane][aj] = bf16x2{x0h, x1h};
      *(bf16x2*)&xA_lo[par][akt][salane][aj] =
          bf16x2{(__bf16)(xv0 - (float)x0h), (__bf16)(xv1 - (float)x1h)};
      *(bf16x2*)&mA[par][akt][salane][aj] = bf16x2{(__bf16)m0, (__bf16)m1};
      *(bf16x2*)&dA_hi[par][akt][salane][aj] = bf16x2{d0h, d1h};
      *(bf16x2*)&dA_lo[par][akt][salane][aj] =
          bf16x2{(__bf16)(d0 - (float)d0h), (__bf16)(d1 - (float)d1h)};
    }
    __syncthreads();  // bar1

    // ---- Phase B: prefetch t+1; delta_h MFMA; h *= exp(-relu); h -> hA ----
    {
      const long to = (long)(t + 1 < TT ? t + 1 : t) * II;
      fx  = *(const f32x2*)(Xp + to);
      fxl = *(const f32x2*)(XLp + to);
      fxm = *(const f32x2*)(XM + to + ai0);
      fm  = __builtin_nontemporal_load((const f32x2*)(MKp + to));
      fd  = __builtin_nontemporal_load((const f32x2*)(DEp + to));

      f32x4 ad = {0.f, 0.f, 0.f, 0.f};
#pragma unroll
      for (int kt = 0; kt < 2; ++kt) {
        bf16x8 ah = *(const bf16x8*)&dA_hi[par][kt][sl][0];
        bf16x8 al = *(const bf16x8*)&dA_lo[par][kt][sl][0];
        ad = mfma16(ah, wgR[kt], ad); ad = mfma16(al, wgR[kt], ad);
      }
#pragma unroll
      for (int r = 0; r < 4; ++r) {
        h[r] *= __expf(-fmaxf(ad[r] + gb, 0.f));
        int srow = qh * 16 + ((lg * 4 + r) ^ (qh << 1));
        __bf16 v = (__bf16)h[r];
        hA_hi[hkt2][srow][hj] = v;
        hA_lo[hkt2][srow][hj] = (__bf16)(h[r] - (float)v);
      }
    }
    __syncthreads();  // bar2

    // ---- Phase C: z,r MFMA (r-weights streamed from L2); write r*h ----
    float zv[4];
    {
      int zoff = 0;
      asm volatile("" : "+v"(zoff));      // opaque 0: keep wr loads in-loop
      const __bf16* wr_t = wzr_base + zoff;
      f32x4 az = {0.f, 0.f, 0.f, 0.f}, ar = {0.f, 0.f, 0.f, 0.f};
#pragma unroll
      for (int kt = 0; kt < 8; ++kt) {
        bf16x8 br = *(const bf16x8*)(wr_t + (kt * 16 + 8 + w) * 512 + l * 8);
        const __bf16* ahp = (kt < 2) ? &xA_hi[par][kt][sl][0]
                          : (kt < 6) ? &hA_hi[kt - 2][sl][0]
                                     : &mA[par][kt - 6][sl][0];
        bf16x8 ah = *(const bf16x8*)ahp;
        az = mfma16(ah, wzR[kt], az);
        ar = mfma16(ah, br, ar);
        if (kt < 6) {
          const __bf16* alp = (kt < 2) ? &xA_lo[par][kt][sl][0]
                                       : &hA_lo[kt - 2][sl][0];
          bf16x8 al = *(const bf16x8*)alp;
          az = mfma16(al, wzR[kt], az);
          ar = mfma16(al, br, ar);
        }
      }
#pragma unroll
      for (int r = 0; r < 4; ++r) {
        zv[r] = sigmoidf_(az[r] + zb);
        float rv = sigmoidf_(ar[r] + rb);
        float rh = rv * h[r];
        int srow = qh * 16 + ((lg * 4 + r) ^ (qh << 1));
        __bf16 v = (__bf16)rh;
        rhA_hi[hkt2][srow][hj] = v;
        rhA_lo[hkt2][srow][hj] = (__bf16)(rh - (float)v);
      }
    }
    __syncthreads();  // bar3

    // ---- Phase D: h_tilde MFMA (h-weights streamed); h update; no barrier ----
    {
      int zoff = 0;
      asm volatile("" : "+v"(zoff));
      const __bf16* wh_t = wh_base + zoff;
      f32x4 ahh = {0.f, 0.f, 0.f, 0.f};
#pragma unroll
      for (int kt = 0; kt < 8; ++kt) {
        bf16x8 bh = *(const bf16x8*)(wh_t + (kt * 8 + w) * 512 + l * 8);
        const __bf16* ahp = (kt < 2) ? &xA_hi[par][kt][sl][0]
                          : (kt < 6) ? &rhA_hi[kt - 2][sl][0]
                                     : &mA[par][kt - 6][sl][0];
        bf16x8 ah = *(const bf16x8*)ahp;
        ahh = mfma16(ah, bh, ahh);
        if (kt < 6) {
          const __bf16* alp = (kt < 2) ? &xA_lo[par][kt][sl][0]
                                       : &rhA_lo[kt - 2][sl][0];
          bf16x8 al = *(const bf16x8*)alp;
          ahh = mfma16(al, bh, ahh);
        }
      }
#pragma unroll
      for (int r = 0; r < 4; ++r) {
        float ht = tanhf_(ahh[r] + hb);
        h[r] = (1.f - zv[r]) * h[r] + zv[r] * ht;
      }
    }
    // no barrier: A(t+1) writes the other parity; hA/rhA untouched by A.
  }

  // ---- fc epilogue ----
#pragma unroll
  for (int r = 0; r < 4; ++r) hstage[lg * 4 + r][cw] = h[r];
  __syncthreads();
  if (tid < BB) {
    float acc = p[pn + OFF_FCB];
    for (int j = 0; j < HH; ++j) acc = fmaf(hstage[tid][j], p[pn + OFF_FCW + j], acc);
    out[n * BATCH + b0 + tid] = sigmoidf_(acc);
  }
}

extern "C" void kernel_launch(void* const* d_in, const int* in_sizes, int n_in,
                              void* d_out, int out_size, void* d_ws, size_t ws_size,
                              hipStream_t stream) {
  const float* p  = (const float*)d_in[0];
  const float* X  = (const float*)d_in[1];
  const float* XL = (const float*)d_in[2];
  const float* XM = (const float*)d_in[3];
  const float* MK = (const float*)d_in[4];
  const float* DE = (const float*)d_in[5];
  float* out = (float*)d_out;
  __bf16* ws = (__bf16*)d_ws;
  if (ws_size < (size_t)WS_ELEMS * 2) return;

  hipLaunchKernelGGL(repack_kernel, dim3(4096), dim3(256), 0, stream, p, ws);
  hipLaunchKernelGGL(grud_main, dim3(NF * (BATCH / BB)), dim3(NTHR), 0, stream,
                     p, X, XL, XM, MK, DE, ws, out);
}

// Round 8
// 361.261 us; speedup vs baseline: 1.5280x; 1.5280x over previous
//
#include <hip/hip_runtime.h>

// GRU-D: nf=64, B=128, T=100, I=64, H=128, C=256.
// R8 = R6 (all weights in regs, BB=32, 1 block/CU) + XOR swizzle + fast
//      tanh/sigmoid + 3 barriers/step (parity x/m planes).
#define NF 64
#define BATCH 128
#define TT 100
#define II 64
#define HH 128
#define CC 256
#define BB 32
#define NTHR 512
#define PSTRIDE 111297

#define OFF_ZW 0
#define OFF_ZB 32768
#define OFF_RW 32896
#define OFF_RB 65664
#define OFF_HW 65792
#define OFF_HB 98560
#define OFF_GXW 98688
#define OFF_GXB 102784
#define OFF_GHW 102848
#define OFF_GHB 111040
#define OFF_FCW 111168
#define OFF_FCB 111296

// ws layout (bf16 elems), per-lane MFMA B-fragment order (hi only)
#define ZR_PER_N 65536
#define H_BASE   (64 * ZR_PER_N)
#define H_PER_N  32768
#define G_BASE   (H_BASE + 64 * H_PER_N)
#define G_PER_N  8192
#define WS_ELEMS (G_BASE + 64 * G_PER_N)   // 6815744 bf16 = 13 MB

typedef __bf16 bf16x8 __attribute__((ext_vector_type(8)));
typedef __bf16 bf16x4 __attribute__((ext_vector_type(4)));
typedef float f32x4 __attribute__((ext_vector_type(4)));

__device__ __forceinline__ f32x4 mfma16(bf16x8 a, bf16x8 b, f32x4 c) {
  return __builtin_amdgcn_mfma_f32_16x16x32_bf16(a, b, c, 0, 0, 0);
}
__device__ __forceinline__ float rcpf_(float x) { return __builtin_amdgcn_rcpf(x); }
__device__ __forceinline__ float sigmoidf_(float x) { return rcpf_(1.f + __expf(-x)); }
__device__ __forceinline__ float tanhf_(float x) {
  float e = __expf(-2.f * __builtin_fabsf(x));
  float t = (1.f - e) * rcpf_(1.f + e);
  return x < 0.f ? -t : t;
}
// row swizzle within a [64][8] plane: physical row = r ^ 2*((r>>4)&3)
__device__ __forceinline__ int SW(int x) { return x ^ (((x >> 4) & 3) << 1); }

// LDS pool element-offsets (each plane = [64 rows][8 j] = 512 elems)
//  xA_hi[par][mt][kt] : 0       (8 planes)
//  xA_lo[par][mt][kt] : 4096
//  mA   [par][mt][kt] : 8192    (8 planes, no lo)
//  dA_hi[mt][kt]      : 12288   (4 planes)
//  dA_lo[mt][kt]      : 14336
//  hA_hi[mt][q4]      : 16384   (8 planes)
//  hA_lo[mt][q4]      : 20480
//  rhA_hi[mt][q4]     : 24576
//  rhA_lo[mt][q4]     : 28672   -> total 32768 elems = 64 KB
#define XAH(par, mt, kt) ((((par)*2 + (mt)) * 2 + (kt)) * 512)
#define XAL(par, mt, kt) (4096 + XAH(par, mt, kt))
#define MAP(par, mt, kt) (8192 + XAH(par, mt, kt))
#define DAH(mt, kt) (12288 + (((mt)*2 + (kt)) * 512))
#define DAL(mt, kt) (2048 + DAH(mt, kt))
#define HAH(mt, q) (16384 + (((mt)*4 + (q)) * 512))
#define HAL(mt, q) (4096 + HAH(mt, q))
#define RHH(mt, q) (8192 + HAH(mt, q))
#define RHL(mt, q) (12288 + HAH(mt, q))

// ---- repack: params -> B-fragment-ordered bf16 (hi only) in ws ----
__global__ void repack_kernel(const float* __restrict__ p, __bf16* __restrict__ ws) {
  const int total = 4194304 + 2097152 + 524288;
  for (int e = blockIdx.x * 256 + threadIdx.x; e < total; e += gridDim.x * 256) {
    float wv; int dst;
    if (e < 4194304) {  // ZR
      int j = e & 7, l = (e >> 3) & 63, nt = (e >> 9) & 15, kt = (e >> 13) & 7, n = e >> 16;
      int c = kt * 32 + (l >> 4) * 8 + j, l15 = l & 15;
      long pn = (long)n * PSTRIDE;
      wv = (nt < 8) ? p[pn + OFF_ZW + (nt * 16 + l15) * CC + c]
                    : p[pn + OFF_RW + ((nt - 8) * 16 + l15) * CC + c];
      dst = n * ZR_PER_N + (kt * 16 + nt) * 512 + l * 8 + j;
    } else if (e < 4194304 + 2097152) {  // H
      int e2 = e - 4194304;
      int j = e2 & 7, l = (e2 >> 3) & 63, nt = (e2 >> 9) & 7, kt = (e2 >> 12) & 7, n = e2 >> 15;
      int c = kt * 32 + (l >> 4) * 8 + j, l15 = l & 15;
      wv = p[(long)n * PSTRIDE + OFF_HW + (nt * 16 + l15) * CC + c];
      dst = H_BASE + n * H_PER_N + (kt * 8 + nt) * 512 + l * 8 + j;
    } else {  // G
      int e2 = e - (4194304 + 2097152);
      int j = e2 & 7, l = (e2 >> 3) & 63, nt = (e2 >> 9) & 7, kt = (e2 >> 12) & 1, n = e2 >> 13;
      int c = kt * 32 + (l >> 4) * 8 + j, l15 = l & 15;
      wv = p[(long)n * PSTRIDE + OFF_GHW + (nt * 16 + l15) * II + c];
      dst = G_BASE + n * G_PER_N + (kt * 8 + nt) * 512 + l * 8 + j;
    }
    ws[dst] = (__bf16)wv;
  }
}

// One block per (n, 32-batch chunk); 8 waves; 1 block/CU (VGPR-bound by design).
__global__ __launch_bounds__(NTHR, 2) void grud_main(
    const float* __restrict__ p, const float* __restrict__ X,
    const float* __restrict__ XL, const float* __restrict__ XM,
    const float* __restrict__ MK, const float* __restrict__ DE,
    const __bf16* __restrict__ ws, float* __restrict__ out) {
  __shared__ __align__(16) __bf16 pool[32768];   // 64 KB, carved per macros

  const int tid = threadIdx.x;
  const int w = tid >> 6, l = tid & 63;
  const int l15 = l & 15, lg = l >> 4;
  const int n = blockIdx.x & 63;            // same-n blocks -> same XCD
  const int b0 = (blockIdx.x >> 6) * BB;
  const long pn = (long)n * PSTRIDE;
  const int cw = w * 16 + l15;
  const int sl = SW(l);                     // physical A-frag read row

  // ---- all weight fragments in registers (loaded once) ----
  bf16x8 wgR[2], wzR[8], wrR[8], whR[8];
  {
    const __bf16* wzr = ws + n * ZR_PER_N;
    const __bf16* wh_ = ws + H_BASE + n * H_PER_N;
    const __bf16* wg_ = ws + G_BASE + n * G_PER_N;
#pragma unroll
    for (int kt = 0; kt < 2; ++kt)
      wgR[kt] = *(const bf16x8*)(wg_ + (kt * 8 + w) * 512 + l * 8);
#pragma unroll
    for (int kt = 0; kt < 8; ++kt) {
      wzR[kt] = *(const bf16x8*)(wzr + (kt * 16 + w) * 512 + l * 8);
      wrR[kt] = *(const bf16x8*)(wzr + (kt * 16 + 8 + w) * 512 + l * 8);
      whR[kt] = *(const bf16x8*)(wh_ + (kt * 8 + w) * 512 + l * 8);
    }
  }

  const float zb = p[pn + OFF_ZB + cw];
  const float rb = p[pn + OFF_RB + cw];
  const float hb = p[pn + OFF_HB + cw];
  const float gb = p[pn + OFF_GHB + cw];

  // this lane's h-column coords (global k = 64 + cw)
  const int hq = ((64 + cw) >> 5) - 2;                 // plane q 0..3
  const int qh = (cw >> 3) & 3;
  const int hj = cw & 7;
  // per-r physical rows (swizzled)
  int hsrow[4];
#pragma unroll
  for (int r = 0; r < 4; ++r) hsrow[r] = qh * 16 + ((lg * 4 + r) ^ (qh << 1));

  // phase-A mapping: thread -> (batch row 0..31, 4-wide i block)
  const int arow = tid >> 4;
  const int ai0 = (tid & 15) * 4;
  const int amt = arow >> 4;
  const int akt = ai0 >> 5;
  const int salane = SW(((ai0 >> 3) & 3) * 16 + (arow & 15));
  const int aj = ai0 & 7;
  const float* __restrict__ Xp  = X  + (long)(b0 + arow) * TT * II + ai0;
  const float* __restrict__ XLp = XL + (long)(b0 + arow) * TT * II + ai0;
  const float* __restrict__ MKp = MK + ((long)(n * BATCH + b0 + arow) * TT) * II + ai0;
  const float* __restrict__ DEp = DE + ((long)(n * BATCH + b0 + arow) * TT) * II + ai0;
  float gxd4[4], gxb4[4];
#pragma unroll
  for (int u = 0; u < 4; ++u) {
    gxd4[u] = p[pn + OFF_GXW + (ai0 + u) * 65];
    gxb4[u] = p[pn + OFF_GXB + ai0 + u];
  }

  float h[2][4] = {{0.f, 0.f, 0.f, 0.f}, {0.f, 0.f, 0.f, 0.f}};

  // prefetch t=0
  f32x4 fx  = *(const f32x4*)Xp;
  f32x4 fxl = *(const f32x4*)XLp;
  f32x4 fxm = *(const f32x4*)(XM + ai0);
  f32x4 fm  = __builtin_nontemporal_load((const f32x4*)MKp);
  f32x4 fd  = __builtin_nontemporal_load((const f32x4*)DEp);

  for (int t = 0; t < TT; ++t) {
    const int par = t & 1;
    // ---- Phase A: elementwise x; write swizzled A-frags (parity planes) ----
    {
      bf16x4 xh, xl_, mh, dh_, dl_;
#pragma unroll
      for (int u = 0; u < 4; ++u) {
        float m = fm[u], d = fd[u];
        float dx = __expf(-fmaxf(fmaf(d, gxd4[u], gxb4[u]), 0.f));
        float xv = m * fx[u] + (1.f - m) * (dx * fxl[u] + (1.f - dx) * fxm[u]);
        __bf16 vh = (__bf16)xv;
        xh[u] = vh; xl_[u] = (__bf16)(xv - (float)vh);
        mh[u] = (__bf16)m;
        __bf16 dvh = (__bf16)d;
        dh_[u] = dvh; dl_[u] = (__bf16)(d - (float)dvh);
      }
      *(bf16x4*)&pool[XAH(par, amt, akt) + salane * 8 + aj] = xh;
      *(bf16x4*)&pool[XAL(par, amt, akt) + salane * 8 + aj] = xl_;
      *(bf16x4*)&pool[MAP(par, amt, akt) + salane * 8 + aj] = mh;
      *(bf16x4*)&pool[DAH(amt, akt) + salane * 8 + aj] = dh_;
      *(bf16x4*)&pool[DAL(amt, akt) + salane * 8 + aj] = dl_;
    }
    __syncthreads();  // bar1

    // ---- Phase B: prefetch t+1; delta_h MFMA; h *= exp(-relu); h -> hA ----
    {
      const long to = (long)(t + 1 < TT ? t + 1 : t) * II;
      fx  = *(const f32x4*)(Xp + to);
      fxl = *(const f32x4*)(XLp + to);
      fxm = *(const f32x4*)(XM + to + ai0);
      fm  = __builtin_nontemporal_load((const f32x4*)(MKp + to));
      fd  = __builtin_nontemporal_load((const f32x4*)(DEp + to));

#pragma unroll
      for (int mt = 0; mt < 2; ++mt) {
        f32x4 ad = {0.f, 0.f, 0.f, 0.f};
#pragma unroll
        for (int kt = 0; kt < 2; ++kt) {
          bf16x8 ah = *(const bf16x8*)&pool[DAH(mt, kt) + sl * 8];
          bf16x8 al = *(const bf16x8*)&pool[DAL(mt, kt) + sl * 8];
          ad = mfma16(ah, wgR[kt], ad); ad = mfma16(al, wgR[kt], ad);
        }
#pragma unroll
        for (int r = 0; r < 4; ++r) {
          h[mt][r] *= __expf(-fmaxf(ad[r] + gb, 0.f));
          __bf16 v = (__bf16)h[mt][r];
          pool[HAH(mt, hq) + hsrow[r] * 8 + hj] = v;
          pool[HAL(mt, hq) + hsrow[r] * 8 + hj] = (__bf16)(h[mt][r] - (float)v);
        }
      }
    }
    __syncthreads();  // bar2

    // ---- Phase C: z,r MFMA; write r*h ----
    float zv[2][4];
#pragma unroll
    for (int mt = 0; mt < 2; ++mt) {
      f32x4 az = {0.f, 0.f, 0.f, 0.f}, ar = {0.f, 0.f, 0.f, 0.f};
#pragma unroll
      for (int kt = 0; kt < 8; ++kt) {
        const __bf16* ahp = (kt < 2) ? &pool[XAH(par, mt, kt) + sl * 8]
                          : (kt < 6) ? &pool[HAH(mt, kt - 2) + sl * 8]
                                     : &pool[MAP(par, mt, kt - 6) + sl * 8];
        bf16x8 ah = *(const bf16x8*)ahp;
        az = mfma16(ah, wzR[kt], az);
        ar = mfma16(ah, wrR[kt], ar);
        if (kt < 6) {
          const __bf16* alp = (kt < 2) ? &pool[XAL(par, mt, kt) + sl * 8]
                                       : &pool[HAL(mt, kt - 2) + sl * 8];
          bf16x8 al = *(const bf16x8*)alp;
          az = mfma16(al, wzR[kt], az);
          ar = mfma16(al, wrR[kt], ar);
        }
      }
#pragma unroll
      for (int r = 0; r < 4; ++r) {
        zv[mt][r] = sigmoidf_(az[r] + zb);
        float rv = sigmoidf_(ar[r] + rb);
        float rh = rv * h[mt][r];
        __bf16 v = (__bf16)rh;
        pool[RHH(mt, hq) + hsrow[r] * 8 + hj] = v;
        pool[RHL(mt, hq) + hsrow[r] * 8 + hj] = (__bf16)(rh - (float)v);
      }
    }
    __syncthreads();  // bar3

    // ---- Phase D: h_tilde MFMA; h update (no trailing barrier) ----
#pragma unroll
    for (int mt = 0; mt < 2; ++mt) {
      f32x4 ahh = {0.f, 0.f, 0.f, 0.f};
#pragma unroll
      for (int kt = 0; kt < 8; ++kt) {
        const __bf16* ahp = (kt < 2) ? &pool[XAH(par, mt, kt) + sl * 8]
                          : (kt < 6) ? &pool[RHH(mt, kt - 2) + sl * 8]
                                     : &pool[MAP(par, mt, kt - 6) + sl * 8];
        bf16x8 ah = *(const bf16x8*)ahp;
        ahh = mfma16(ah, whR[kt], ahh);
        if (kt < 6) {
          const __bf16* alp = (kt < 2) ? &pool[XAL(par, mt, kt) + sl * 8]
                                       : &pool[RHL(mt, kt - 2) + sl * 8];
          bf16x8 al = *(const bf16x8*)alp;
          ahh = mfma16(al, whR[kt], ahh);
        }
      }
#pragma unroll
      for (int r = 0; r < 4; ++r) {
        float ht = tanhf_(ahh[r] + hb);
        h[mt][r] = (1.f - zv[mt][r]) * h[mt][r] + zv[mt][r] * ht;
      }
    }
    // Phase A(t+1) writes the other parity / dA (re-read only after 2 barriers).
  }

  // ---- fc epilogue (hstage aliases dead pool planes) ----
  __syncthreads();
  float* hst = (float*)pool;                 // [32][132]
#pragma unroll
  for (int mt = 0; mt < 2; ++mt)
#pragma unroll
    for (int r = 0; r < 4; ++r) hst[(mt * 16 + lg * 4 + r) * 132 + cw] = h[mt][r];
  __syncthreads();
  if (tid < BB) {
    float acc = p[pn + OFF_FCB];
    for (int j = 0; j < HH; ++j) acc = fmaf(hst[tid * 132 + j], p[pn + OFF_FCW + j], acc);
    out[n * BATCH + b0 + tid] = sigmoidf_(acc);
  }
}

extern "C" void kernel_launch(void* const* d_in, const int* in_sizes, int n_in,
                              void* d_out, int out_size, void* d_ws, size_t ws_size,
                              hipStream_t stream) {
  const float* p  = (const float*)d_in[0];
  const float* X  = (const float*)d_in[1];
  const float* XL = (const float*)d_in[2];
  const float* XM = (const float*)d_in[3];
  const float* MK = (const float*)d_in[4];
  const float* DE = (const float*)d_in[5];
  float* out = (float*)d_out;
  __bf16* ws = (__bf16*)d_ws;
  if (ws_size < (size_t)WS_ELEMS * 2) return;

  hipLaunchKernelGGL(repack_kernel, dim3(4096), dim3(256), 0, stream, p, ws);
  hipLaunchKernelGGL(grud_main, dim3(NF * (BATCH / BB)), dim3(NTHR), 0, stream,
                     p, X, XL, XM, MK, DE, ws, out);
}

// Round 9
// 328.777 us; speedup vs baseline: 1.6790x; 1.0988x over previous
//
#include <hip/hip_runtime.h>

// GRU-D: nf=64, B=128, T=100, I=64, H=128, C=256.
// R9 = R8 + (a) drop x_lo/d_lo (keep h/rh hi+lo), (b) 2 barriers/step:
//      phase A(t+1) fused into C-region, delta_h MFMA + decay fused into D-region.
#define NF 64
#define BATCH 128
#define TT 100
#define II 64
#define HH 128
#define CC 256
#define BB 32
#define NTHR 512
#define PSTRIDE 111297

#define OFF_ZW 0
#define OFF_ZB 32768
#define OFF_RW 32896
#define OFF_RB 65664
#define OFF_HW 65792
#define OFF_HB 98560
#define OFF_GXW 98688
#define OFF_GXB 102784
#define OFF_GHW 102848
#define OFF_GHB 111040
#define OFF_FCW 111168
#define OFF_FCB 111296

// ws layout (bf16 elems), per-lane MFMA B-fragment order (hi only)
#define ZR_PER_N 65536
#define H_BASE   (64 * ZR_PER_N)
#define H_PER_N  32768
#define G_BASE   (H_BASE + 64 * H_PER_N)
#define G_PER_N  8192
#define WS_ELEMS (G_BASE + 64 * G_PER_N)   // 6815744 bf16 = 13 MB

typedef __bf16 bf16x8 __attribute__((ext_vector_type(8)));
typedef __bf16 bf16x4 __attribute__((ext_vector_type(4)));
typedef float f32x4 __attribute__((ext_vector_type(4)));

__device__ __forceinline__ f32x4 mfma16(bf16x8 a, bf16x8 b, f32x4 c) {
  return __builtin_amdgcn_mfma_f32_16x16x32_bf16(a, b, c, 0, 0, 0);
}
__device__ __forceinline__ float rcpf_(float x) { return __builtin_amdgcn_rcpf(x); }
__device__ __forceinline__ float sigmoidf_(float x) { return rcpf_(1.f + __expf(-x)); }
__device__ __forceinline__ float tanhf_(float x) {
  float e = __expf(-2.f * __builtin_fabsf(x));
  float t = (1.f - e) * rcpf_(1.f + e);
  return x < 0.f ? -t : t;
}
// row swizzle within a [64][8] plane: physical row = r ^ 2*((r>>4)&3)
__device__ __forceinline__ int SW(int x) { return x ^ (((x >> 4) & 3) << 1); }

// LDS pool element-offsets (plane = [64 rows][8 j] = 512 elems):
//  XA(par,mt,kt)  x hi       : [0, 4096)
//  MAPL(par,mt,kt) mask      : [4096, 8192)
//  DAH(mt,kt)     d hi       : [8192, 10240)
//  HAH/HAL(mt,q)  h hi/lo    : [10240, 18432)
//  RHH/RHL(mt,q)  r*h hi/lo  : [18432, 26624)
#define XA(par, mt, kt)  ((((par)*2 + (mt)) * 2 + (kt)) * 512)
#define MAPL(par, mt, kt) (4096 + XA(par, mt, kt))
#define DAH(mt, kt) (8192 + (((mt)*2 + (kt)) * 512))
#define HAH(mt, q) (10240 + (((mt)*4 + (q)) * 512))
#define HAL(mt, q) (14336 + (((mt)*4 + (q)) * 512))
#define RHH(mt, q) (18432 + (((mt)*4 + (q)) * 512))
#define RHL(mt, q) (22528 + (((mt)*4 + (q)) * 512))
#define POOL_ELEMS 26624

// ---- repack: params -> B-fragment-ordered bf16 (hi only) in ws ----
__global__ void repack_kernel(const float* __restrict__ p, __bf16* __restrict__ ws) {
  const int total = 4194304 + 2097152 + 524288;
  for (int e = blockIdx.x * 256 + threadIdx.x; e < total; e += gridDim.x * 256) {
    float wv; int dst;
    if (e < 4194304) {  // ZR
      int j = e & 7, l = (e >> 3) & 63, nt = (e >> 9) & 15, kt = (e >> 13) & 7, n = e >> 16;
      int c = kt * 32 + (l >> 4) * 8 + j, l15 = l & 15;
      long pn = (long)n * PSTRIDE;
      wv = (nt < 8) ? p[pn + OFF_ZW + (nt * 16 + l15) * CC + c]
                    : p[pn + OFF_RW + ((nt - 8) * 16 + l15) * CC + c];
      dst = n * ZR_PER_N + (kt * 16 + nt) * 512 + l * 8 + j;
    } else if (e < 4194304 + 2097152) {  // H
      int e2 = e - 4194304;
      int j = e2 & 7, l = (e2 >> 3) & 63, nt = (e2 >> 9) & 7, kt = (e2 >> 12) & 7, n = e2 >> 15;
      int c = kt * 32 + (l >> 4) * 8 + j, l15 = l & 15;
      wv = p[(long)n * PSTRIDE + OFF_HW + (nt * 16 + l15) * CC + c];
      dst = H_BASE + n * H_PER_N + (kt * 8 + nt) * 512 + l * 8 + j;
    } else {  // G
      int e2 = e - (4194304 + 2097152);
      int j = e2 & 7, l = (e2 >> 3) & 63, nt = (e2 >> 9) & 7, kt = (e2 >> 12) & 1, n = e2 >> 13;
      int c = kt * 32 + (l >> 4) * 8 + j, l15 = l & 15;
      wv = p[(long)n * PSTRIDE + OFF_GHW + (nt * 16 + l15) * II + c];
      dst = G_BASE + n * G_PER_N + (kt * 8 + nt) * 512 + l * 8 + j;
    }
    ws[dst] = (__bf16)wv;
  }
}

// One block per (n, 32-batch chunk); 8 waves; 1 block/CU.
__global__ __launch_bounds__(NTHR, 2) void grud_main(
    const float* __restrict__ p, const float* __restrict__ X,
    const float* __restrict__ XL, const float* __restrict__ XM,
    const float* __restrict__ MK, const float* __restrict__ DE,
    const __bf16* __restrict__ ws, float* __restrict__ out) {
  __shared__ __align__(16) __bf16 pool[POOL_ELEMS];

  const int tid = threadIdx.x;
  const int w = tid >> 6, l = tid & 63;
  const int l15 = l & 15, lg = l >> 4;
  const int n = blockIdx.x & 63;            // same-n blocks -> same XCD
  const int b0 = (blockIdx.x >> 6) * BB;
  const long pn = (long)n * PSTRIDE;
  const int cw = w * 16 + l15;
  const int sl = SW(l);

  // ---- all weight fragments in registers (loaded once, 104 VGPR) ----
  bf16x8 wgR[2], wzR[8], wrR[8], whR[8];
  {
    const __bf16* wzr = ws + n * ZR_PER_N;
    const __bf16* wh_ = ws + H_BASE + n * H_PER_N;
    const __bf16* wg_ = ws + G_BASE + n * G_PER_N;
#pragma unroll
    for (int kt = 0; kt < 2; ++kt)
      wgR[kt] = *(const bf16x8*)(wg_ + (kt * 8 + w) * 512 + l * 8);
#pragma unroll
    for (int kt = 0; kt < 8; ++kt) {
      wzR[kt] = *(const bf16x8*)(wzr + (kt * 16 + w) * 512 + l * 8);
      wrR[kt] = *(const bf16x8*)(wzr + (kt * 16 + 8 + w) * 512 + l * 8);
      whR[kt] = *(const bf16x8*)(wh_ + (kt * 8 + w) * 512 + l * 8);
    }
  }

  const float zb = p[pn + OFF_ZB + cw];
  const float rb = p[pn + OFF_RB + cw];
  const float hb = p[pn + OFF_HB + cw];
  const float gb = p[pn + OFF_GHB + cw];

  // this lane's h-column coords (global k = 64 + cw)
  const int hq = ((64 + cw) >> 5) - 2;                 // plane q 0..3
  const int qh = (cw >> 3) & 3;
  const int hj = cw & 7;
  int hsrow[4];
#pragma unroll
  for (int r = 0; r < 4; ++r) hsrow[r] = qh * 16 + ((lg * 4 + r) ^ (qh << 1));

  // phase-A mapping: thread -> (batch row 0..31, 4-wide i block)
  const int arow = tid >> 4;
  const int ai0 = (tid & 15) * 4;
  const int amt = arow >> 4;
  const int akt = ai0 >> 5;
  const int salane = SW(((ai0 >> 3) & 3) * 16 + (arow & 15));
  const int aj = ai0 & 7;
  const float* __restrict__ Xp  = X  + (long)(b0 + arow) * TT * II + ai0;
  const float* __restrict__ XLp = XL + (long)(b0 + arow) * TT * II + ai0;
  const float* __restrict__ MKp = MK + ((long)(n * BATCH + b0 + arow) * TT) * II + ai0;
  const float* __restrict__ DEp = DE + ((long)(n * BATCH + b0 + arow) * TT) * II + ai0;
  float gxd4[4], gxb4[4];
#pragma unroll
  for (int u = 0; u < 4; ++u) {
    gxd4[u] = p[pn + OFF_GXW + (ai0 + u) * 65];
    gxb4[u] = p[pn + OFF_GXB + ai0 + u];
  }

  float h[2][4] = {{0.f, 0.f, 0.f, 0.f}, {0.f, 0.f, 0.f, 0.f}};

  // ---- prologue: zero hA planes; A(0); prefetch(1) ----
  for (int e = tid; e < 8192; e += NTHR) pool[10240 + e] = (__bf16)0.f;

  f32x4 fx  = *(const f32x4*)Xp;
  f32x4 fxl = *(const f32x4*)XLp;
  f32x4 fxm = *(const f32x4*)(XM + ai0);
  f32x4 fm  = __builtin_nontemporal_load((const f32x4*)MKp);
  f32x4 fd  = __builtin_nontemporal_load((const f32x4*)DEp);
  {
    bf16x4 xh, mh;
#pragma unroll
    for (int u = 0; u < 4; ++u) {
      float m = fm[u], d = fd[u];
      float dx = __expf(-fmaxf(fmaf(d, gxd4[u], gxb4[u]), 0.f));
      float xv = m * fx[u] + (1.f - m) * (dx * fxl[u] + (1.f - dx) * fxm[u]);
      xh[u] = (__bf16)xv;
      mh[u] = (__bf16)m;
    }
    *(bf16x4*)&pool[XA(0, amt, akt) + salane * 8 + aj] = xh;
    *(bf16x4*)&pool[MAPL(0, amt, akt) + salane * 8 + aj] = mh;
  }
  {
    const long to = (long)(TT > 1 ? 1 : 0) * II;
    fx  = *(const f32x4*)(Xp + to);
    fxl = *(const f32x4*)(XLp + to);
    fxm = *(const f32x4*)(XM + to + ai0);
    fm  = __builtin_nontemporal_load((const f32x4*)(MKp + to));
    fd  = __builtin_nontemporal_load((const f32x4*)(DEp + to));
  }
  __syncthreads();

  for (int t = 0; t < TT; ++t) {
    const int par = t & 1, parn = par ^ 1;
    const bool more = (t + 1 < TT);

    // ================= C-region =================
    // A(t+1): elementwise from prefetched regs -> parn planes + dA
    if (more) {
      bf16x4 xh, mh, dh;
#pragma unroll
      for (int u = 0; u < 4; ++u) {
        float m = fm[u], d = fd[u];
        float dx = __expf(-fmaxf(fmaf(d, gxd4[u], gxb4[u]), 0.f));
        float xv = m * fx[u] + (1.f - m) * (dx * fxl[u] + (1.f - dx) * fxm[u]);
        xh[u] = (__bf16)xv;
        mh[u] = (__bf16)m;
        dh[u] = (__bf16)d;
      }
      *(bf16x4*)&pool[XA(parn, amt, akt) + salane * 8 + aj] = xh;
      *(bf16x4*)&pool[MAPL(parn, amt, akt) + salane * 8 + aj] = mh;
      *(bf16x4*)&pool[DAH(amt, akt) + salane * 8 + aj] = dh;
      // prefetch t+2
      const long to = (long)(t + 2 < TT ? t + 2 : TT - 1) * II;
      fx  = *(const f32x4*)(Xp + to);
      fxl = *(const f32x4*)(XLp + to);
      fxm = *(const f32x4*)(XM + to + ai0);
      fm  = __builtin_nontemporal_load((const f32x4*)(MKp + to));
      fd  = __builtin_nontemporal_load((const f32x4*)(DEp + to));
    }

    // z,r MFMA over comb(par)
    float zv[2][4];
#pragma unroll
    for (int mt = 0; mt < 2; ++mt) {
      f32x4 az = {0.f, 0.f, 0.f, 0.f}, ar = {0.f, 0.f, 0.f, 0.f};
#pragma unroll
      for (int kt = 0; kt < 8; ++kt) {
        const __bf16* ahp = (kt < 2) ? &pool[XA(par, mt, kt) + sl * 8]
                          : (kt < 6) ? &pool[HAH(mt, kt - 2) + sl * 8]
                                     : &pool[MAPL(par, mt, kt - 6) + sl * 8];
        bf16x8 ah = *(const bf16x8*)ahp;
        az = mfma16(ah, wzR[kt], az);
        ar = mfma16(ah, wrR[kt], ar);
        if (kt >= 2 && kt < 6) {  // h-region lo term
          bf16x8 al = *(const bf16x8*)&pool[HAL(mt, kt - 2) + sl * 8];
          az = mfma16(al, wzR[kt], az);
          ar = mfma16(al, wrR[kt], ar);
        }
      }
#pragma unroll
      for (int r = 0; r < 4; ++r) {
        zv[mt][r] = sigmoidf_(az[r] + zb);
        float rv = sigmoidf_(ar[r] + rb);
        float rh = rv * h[mt][r];
        __bf16 v = (__bf16)rh;
        pool[RHH(mt, hq) + hsrow[r] * 8 + hj] = v;
        pool[RHL(mt, hq) + hsrow[r] * 8 + hj] = (__bf16)(rh - (float)v);
      }
    }
    __syncthreads();  // bar1

    // ================= D-region =================
#pragma unroll
    for (int mt = 0; mt < 2; ++mt) {
      f32x4 ahh = {0.f, 0.f, 0.f, 0.f};
#pragma unroll
      for (int kt = 0; kt < 8; ++kt) {
        const __bf16* ahp = (kt < 2) ? &pool[XA(par, mt, kt) + sl * 8]
                          : (kt < 6) ? &pool[RHH(mt, kt - 2) + sl * 8]
                                     : &pool[MAPL(par, mt, kt - 6) + sl * 8];
        bf16x8 ah = *(const bf16x8*)ahp;
        ahh = mfma16(ah, whR[kt], ahh);
        if (kt >= 2 && kt < 6) {
          bf16x8 al = *(const bf16x8*)&pool[RHL(mt, kt - 2) + sl * 8];
          ahh = mfma16(al, whR[kt], ahh);
        }
      }
      // delta_h(t+1) matmul (h-independent)
      f32x4 ad = {0.f, 0.f, 0.f, 0.f};
      if (more) {
#pragma unroll
        for (int kt = 0; kt < 2; ++kt) {
          bf16x8 ah = *(const bf16x8*)&pool[DAH(mt, kt) + sl * 8];
          ad = mfma16(ah, wgR[kt], ad);
        }
      }
#pragma unroll
      for (int r = 0; r < 4; ++r) {
        float ht = tanhf_(ahh[r] + hb);
        float hn = (1.f - zv[mt][r]) * h[mt][r] + zv[mt][r] * ht;
        if (more) {
          hn *= __expf(-fmaxf(ad[r] + gb, 0.f));   // decay for step t+1
          __bf16 v = (__bf16)hn;
          pool[HAH(mt, hq) + hsrow[r] * 8 + hj] = v;
          pool[HAL(mt, hq) + hsrow[r] * 8 + hj] = (__bf16)(hn - (float)v);
        }
        h[mt][r] = hn;
      }
    }
    __syncthreads();  // bar2
  }

  // ---- fc epilogue (overlays pool) ----
  float* hst = (float*)pool;                 // [32][132]
#pragma unroll
  for (int mt = 0; mt < 2; ++mt)
#pragma unroll
    for (int r = 0; r < 4; ++r) hst[(mt * 16 + lg * 4 + r) * 132 + cw] = h[mt][r];
  __syncthreads();
  if (tid < BB) {
    float acc = p[pn + OFF_FCB];
    for (int j = 0; j < HH; ++j) acc = fmaf(hst[tid * 132 + j], p[pn + OFF_FCW + j], acc);
    out[n * BATCH + b0 + tid] = sigmoidf_(acc);
  }
}

extern "C" void kernel_launch(void* const* d_in, const int* in_sizes, int n_in,
                              void* d_out, int out_size, void* d_ws, size_t ws_size,
                              hipStream_t stream) {
  const float* p  = (const float*)d_in[0];
  const float* X  = (const float*)d_in[1];
  const float* XL = (const float*)d_in[2];
  const float* XM = (const float*)d_in[3];
  const float* MK = (const float*)d_in[4];
  const float* DE = (const float*)d_in[5];
  float* out = (float*)d_out;
  __bf16* ws = (__bf16*)d_ws;
  if (ws_size < (size_t)WS_ELEMS * 2) return;

  hipLaunchKernelGGL(repack_kernel, dim3(4096), dim3(256), 0, stream, p, ws);
  hipLaunchKernelGGL(grud_main, dim3(NF * (BATCH / BB)), dim3(NTHR), 0, stream,
                     p, X, XL, XM, MK, DE, ws, out);
}